// Round 3
// baseline (37.996 us; speedup 1.0000x reference)
//
#include <hip/hip_runtime.h>

// ---------------------------------------------------------------------------
// Compile-time Clebsch-Gordan machinery (direct port of the reference Python).
// All coefficients fold to FMA immediates in the kernel.
// ---------------------------------------------------------------------------

struct Cx { double r, i; };

constexpr double ffact(int n) {
    double v = 1.0;
    for (int i = 2; i <= n; ++i) v *= (double)i;
    return v;
}

constexpr double csqrt_(double x) {
    if (x <= 0.0) return 0.0;
    double g = x < 1.0 ? 1.0 : x;
    for (int i = 0; i < 48; ++i) g = 0.5 * (g + x / g);
    return g;
}

// Complex-basis CG <j1 m1 j2 m2 | j3 m3> (Racah formula), as in the reference.
constexpr double cgc(int j1, int m1, int j2, int m2, int j3, int m3) {
    if (m1 + m2 != m3) return 0.0;
    if (m1 < -j1 || m1 > j1 || m2 < -j2 || m2 > j2 || m3 < -j3 || m3 > j3) return 0.0;
    double pref = csqrt_((2.0 * j3 + 1.0) * ffact(j3 + j1 - j2) * ffact(j3 - j1 + j2) *
                         ffact(j1 + j2 - j3) / ffact(j1 + j2 + j3 + 1));
    pref *= csqrt_(ffact(j3 + m3) * ffact(j3 - m3) * ffact(j1 - m1) * ffact(j1 + m1) *
                   ffact(j2 - m2) * ffact(j2 + m2));
    double s = 0.0;
    for (int k = 0; k <= j1 + j2 - j3; ++k) {
        const int d0 = k, d1 = j1 + j2 - j3 - k, d2 = j1 - m1 - k;
        const int d3 = j2 + m2 - k, d4 = j3 - j2 + m1 + k, d5 = j3 - j1 - m2 + k;
        if (d0 < 0 || d1 < 0 || d2 < 0 || d3 < 0 || d4 < 0 || d5 < 0) continue;
        const double den = ffact(d0) * ffact(d1) * ffact(d2) * ffact(d3) * ffact(d4) * ffact(d5);
        s += ((k & 1) ? -1.0 : 1.0) / den;
    }
    return pref * s;
}

// Entry (row a, col m) of the complex->real change-of-basis matrix Q for level l.
constexpr Cx qent(int l, int a, int m) {
    Cx z{0.0, 0.0};
    if (l == 0) { if (a == 0 && m == 0) z.r = 1.0; return z; }
    if (a == l) { if (m == l) z.r = 1.0; return z; }
    const double is = 0.70710678118654752440;  // 1/sqrt(2)
    if (a > l) {
        const int mm = a - l;
        if (m == l + mm)      z.r = (mm & 1) ? -is : is;   // (-1)^m / sqrt2
        else if (m == l - mm) z.r = is;                    // 1 / sqrt2
    } else {
        const int mm = l - a;
        if (m == l - mm)      z.i = is;                    // i / sqrt2
        else if (m == l + mm) z.i = (mm & 1) ? is : -is;   // -i(-1)^m / sqrt2
    }
    return z;
}

// Real-basis CG tensor for one path (l1, l2) -> l3.
template <int L1, int L2, int L3>
struct PathT {
    double v[2 * L1 + 1][2 * L2 + 1][2 * L3 + 1];
    constexpr PathT() : v{} {
        double CG[2 * L1 + 1][2 * L2 + 1][2 * L3 + 1] = {};
        for (int m = 0; m <= 2 * L1; ++m)
            for (int n = 0; n <= 2 * L2; ++n)
                for (int o = 0; o <= 2 * L3; ++o)
                    CG[m][n][o] = cgc(L1, m - L1, L2, n - L2, L3, o - L3);
        Cx Q1[2 * L1 + 1][2 * L1 + 1] = {};
        Cx Q2[2 * L2 + 1][2 * L2 + 1] = {};
        Cx Q3[2 * L3 + 1][2 * L3 + 1] = {};
        for (int a = 0; a <= 2 * L1; ++a) for (int m = 0; m <= 2 * L1; ++m) Q1[a][m] = qent(L1, a, m);
        for (int b = 0; b <= 2 * L2; ++b) for (int n = 0; n <= 2 * L2; ++n) Q2[b][n] = qent(L2, b, n);
        for (int c = 0; c <= 2 * L3; ++c) for (int o = 0; o <= 2 * L3; ++o) Q3[c][o] = qent(L3, c, o);
        for (int a = 0; a <= 2 * L1; ++a)
            for (int b = 0; b <= 2 * L2; ++b)
                for (int c = 0; c <= 2 * L3; ++c) {
                    double re = 0.0;
                    for (int m = 0; m <= 2 * L1; ++m)
                        for (int n = 0; n <= 2 * L2; ++n)
                            for (int o = 0; o <= 2 * L3; ++o) {
                                const double cg = CG[m][n][o];
                                if (cg == 0.0) continue;
                                const Cx q1 = Q1[a][m], q2 = Q2[b][n], q3 = Q3[c][o];
                                const double tr = q1.r * q2.r - q1.i * q2.i;
                                const double ti = q1.r * q2.i + q1.i * q2.r;
                                re += (tr * q3.r + ti * q3.i) * cg;
                            }
                    v[a][b][c] = re;
                }
    }
};

static constexpr PathT<0, 0, 0> C000{};
static constexpr PathT<1, 1, 0> C110{};
static constexpr PathT<2, 2, 0> C220{};
static constexpr PathT<0, 1, 1> C011{};
static constexpr PathT<1, 0, 1> C101{};
static constexpr PathT<1, 2, 1> C121{};
static constexpr PathT<2, 1, 1> C211{};
static constexpr PathT<0, 2, 2> C022{};
static constexpr PathT<1, 1, 2> C112{};
static constexpr PathT<2, 0, 2> C202{};
static constexpr PathT<2, 2, 2> C222{};
static constexpr PathT<1, 2, 3> C123{};
static constexpr PathT<2, 1, 3> C213{};

static_assert(C000.v[0][0][0] > 0.999 && C000.v[0][0][0] < 1.001, "C000 must be 1");
static_assert(C110.v[0][0][0] < -0.577 && C110.v[0][0][0] > -0.578, "C110 diag must be -1/sqrt3");
static_assert(C110.v[0][1][0] > -1e-9 && C110.v[0][1][0] < 1e-9, "C110 off-diag must be 0");
static_assert(C220.v[2][2][0] > 0.447 && C220.v[2][2][0] < 0.448, "C220 diag must be +1/sqrt5");
static_assert(C011.v[0][1][1] > 0.999 && C011.v[0][1][1] < 1.001, "C011 must be identity");
static_assert(C022.v[0][3][3] > 0.999 && C022.v[0][3][3] < 1.001, "C022 must be identity");

// ---------------------------------------------------------------------------
// Per-row math (proven correct in round 1).
// ---------------------------------------------------------------------------

__device__ __forceinline__ void compute_row(const float* __restrict__ xs,
                                            const float* W0, const float* W1,
                                            const float* W2, const float* W3,
                                            float B0, float k0, float k1, float k2,
                                            float* __restrict__ o) {
    const float s = xs[0];

    // ---- l3 = 0 ----
    {
        const float z0 = (float)C000.v[0][0][0] * s * s;
        float z1 = 0.f;
#pragma unroll
        for (int a = 0; a < 3; ++a)
#pragma unroll
            for (int b = 0; b < 3; ++b) {
                const float cv = (float)C110.v[a][b][0];
                if (cv != 0.f) z1 += cv * xs[1 + a] * xs[1 + b];
            }
        float z2 = 0.f;
#pragma unroll
        for (int a = 0; a < 5; ++a)
#pragma unroll
            for (int b = 0; b < 5; ++b) {
                const float cv = (float)C220.v[a][b][0];
                if (cv != 0.f) z2 += cv * xs[4 + a] * xs[4 + b];
            }
        o[0] = (W0[0] * z0 + W0[1] * z1 + W0[2] * z2) * 0.57735026918962576f + B0 + k0 * s;
    }

    // ---- l3 = 1 ----
    {
        float za[3] = {}, zb[3] = {}, zc[3] = {}, zd[3] = {};
#pragma unroll
        for (int b = 0; b < 3; ++b)
#pragma unroll
            for (int c = 0; c < 3; ++c) {
                const float cv = (float)C011.v[0][b][c];
                if (cv != 0.f) za[c] += cv * s * xs[1 + b];
            }
#pragma unroll
        for (int a = 0; a < 3; ++a)
#pragma unroll
            for (int c = 0; c < 3; ++c) {
                const float cv = (float)C101.v[a][0][c];
                if (cv != 0.f) zb[c] += cv * xs[1 + a] * s;
            }
#pragma unroll
        for (int a = 0; a < 3; ++a)
#pragma unroll
            for (int b = 0; b < 5; ++b)
#pragma unroll
                for (int c = 0; c < 3; ++c) {
                    const float cv = (float)C121.v[a][b][c];
                    if (cv != 0.f) zc[c] += cv * xs[1 + a] * xs[4 + b];
                }
#pragma unroll
        for (int a = 0; a < 5; ++a)
#pragma unroll
            for (int b = 0; b < 3; ++b)
#pragma unroll
                for (int c = 0; c < 3; ++c) {
                    const float cv = (float)C211.v[a][b][c];
                    if (cv != 0.f) zd[c] += cv * xs[4 + a] * xs[1 + b];
                }
#pragma unroll
        for (int c = 0; c < 3; ++c)
            o[1 + c] = (W1[0] * za[c] + W1[1] * zb[c] + W1[2] * zc[c] + W1[3] * zd[c]) * 0.5f
                       + k1 * xs[1 + c];
    }

    // ---- l3 = 2 ----
    {
        float za[5] = {}, zb[5] = {}, zc[5] = {}, zd[5] = {};
#pragma unroll
        for (int b = 0; b < 5; ++b)
#pragma unroll
            for (int c = 0; c < 5; ++c) {
                const float cv = (float)C022.v[0][b][c];
                if (cv != 0.f) za[c] += cv * s * xs[4 + b];
            }
#pragma unroll
        for (int a = 0; a < 3; ++a)
#pragma unroll
            for (int b = 0; b < 3; ++b)
#pragma unroll
                for (int c = 0; c < 5; ++c) {
                    const float cv = (float)C112.v[a][b][c];
                    if (cv != 0.f) zb[c] += cv * xs[1 + a] * xs[1 + b];
                }
#pragma unroll
        for (int a = 0; a < 5; ++a)
#pragma unroll
            for (int c = 0; c < 5; ++c) {
                const float cv = (float)C202.v[a][0][c];
                if (cv != 0.f) zc[c] += cv * xs[4 + a] * s;
            }
#pragma unroll
        for (int a = 0; a < 5; ++a)
#pragma unroll
            for (int b = 0; b < 5; ++b)
#pragma unroll
                for (int c = 0; c < 5; ++c) {
                    const float cv = (float)C222.v[a][b][c];
                    if (cv != 0.f) zd[c] += cv * xs[4 + a] * xs[4 + b];
                }
#pragma unroll
        for (int c = 0; c < 5; ++c)
            o[4 + c] = (W2[0] * za[c] + W2[1] * zb[c] + W2[2] * zc[c] + W2[3] * zd[c]) * 0.5f
                       + k2 * xs[4 + c];
    }

    // ---- l3 = 3 ----
    {
        float za[7] = {}, zb[7] = {};
#pragma unroll
        for (int a = 0; a < 3; ++a)
#pragma unroll
            for (int b = 0; b < 5; ++b)
#pragma unroll
                for (int c = 0; c < 7; ++c) {
                    const float cv = (float)C123.v[a][b][c];
                    if (cv != 0.f) za[c] += cv * xs[1 + a] * xs[4 + b];
                }
#pragma unroll
        for (int a = 0; a < 5; ++a)
#pragma unroll
            for (int b = 0; b < 3; ++b)
#pragma unroll
                for (int c = 0; c < 7; ++c) {
                    const float cv = (float)C213.v[a][b][c];
                    if (cv != 0.f) zb[c] += cv * xs[4 + a] * xs[1 + b];
                }
#pragma unroll
        for (int c = 0; c < 7; ++c)
            o[9 + c] = (W3[0] * za[c] + W3[1] * zb[c]) * 0.70710678118654752440f;
    }
}

// ---------------------------------------------------------------------------
// Kernel: block of 256 threads handles 256 rows. All global traffic is fully
// coalesced via LDS staging. Out-staging uses a 20-word (80 B) row stride:
// 16B-aligned (b128-legal) and 20 mod 32 spreads 16B chunks uniformly over
// all 32 banks (8 words/bank = structural minimum) for BOTH the write phase
// (lane-major) and the readback phase (row-major) -> conflict-free.
// ---------------------------------------------------------------------------

#define SO_STRIDE 20

__global__ __launch_bounds__(256) void e3_selfmix_kernel(
    const float* __restrict__ x, const float* __restrict__ w0,
    const float* __restrict__ w1, const float* __restrict__ w2,
    const float* __restrict__ w3, const float* __restrict__ b0,
    const float* __restrict__ kg, float* __restrict__ out,
    int nrows, int C) {
    __shared__ __align__(16) float sx[256 * 9];          // 9216 B
    __shared__ __align__(16) float so[256 * SO_STRIDE];  // 20480 B
    __shared__ __align__(16) float sk[384];              // 1536 B

    const int t = threadIdx.x;
    const long long blockBase = (long long)blockIdx.x * 256;
    const int rows_here = min(256, (int)(nrows - blockBase));
    const float* __restrict__ xg = x + blockBase * 9;
    float* __restrict__ og = out + blockBase * 16;

    // ---- stage k (C==128: whole table, 96 coalesced float4 loads) ----
    const bool kfast = (C == 128);
    if (kfast && t < 96)
        *reinterpret_cast<float4*>(&sk[t * 4]) = reinterpret_cast<const float4*>(kg)[t];

    // ---- stage x: 576 float4 = 2304 floats, fully coalesced ----
    if (rows_here == 256) {
        const float4* __restrict__ xg4 = reinterpret_cast<const float4*>(xg);
#pragma unroll
        for (int i = 0; i < 3; ++i) {
            const int idx = i * 256 + t;
            if (idx < 576)
                *reinterpret_cast<float4*>(&sx[idx * 4]) = xg4[idx];
        }
    } else {
        for (int w = t; w < rows_here * 9; w += 256) sx[w] = xg[w];
    }
    __syncthreads();

    // ---- compute ----
    if (t < rows_here) {
        // Wave-uniform parameters (scalarized by the compiler).
        const float W0[3] = {w0[0], w0[1], w0[2]};
        const float W1[4] = {w1[0], w1[1], w1[2], w1[3]};
        const float W2[4] = {w2[0], w2[1], w2[2], w2[3]};
        const float W3[2] = {w3[0], w3[1]};
        const float B0 = b0[0];

        float xs[9];
#pragma unroll
        for (int j = 0; j < 9; ++j) xs[j] = sx[t * 9 + j];

        float k0, k1, k2;
        if (kfast) {
            const int ch3 = (t & 127) * 3;  // blockBase is a multiple of 128
            k0 = sk[ch3]; k1 = sk[ch3 + 1]; k2 = sk[ch3 + 2];
        } else {
            const long long ch = (blockBase + t) % C;
            k0 = kg[ch * 3]; k1 = kg[ch * 3 + 1]; k2 = kg[ch * 3 + 2];
        }

        float o[16];
        compute_row(xs, W0, W1, W2, W3, B0, k0, k1, k2, o);

        // 4x ds_write_b128; bank starts cycle all 8 disjoint 4-bank spans.
#pragma unroll
        for (int q = 0; q < 4; ++q)
            *reinterpret_cast<float4*>(&so[t * SO_STRIDE + q * 4]) =
                make_float4(o[4 * q], o[4 * q + 1], o[4 * q + 2], o[4 * q + 3]);
    }
    __syncthreads();

    // ---- coalesced store: 4x ds_read_b128 + 4x global_store_dwordx4 ----
    if (rows_here == 256) {
        float4* __restrict__ og4 = reinterpret_cast<float4*>(og);
#pragma unroll
        for (int i = 0; i < 4; ++i) {
            const int p4 = i * 256 + t;          // float4 index: row p4>>2, quad p4&3
            const int r = p4 >> 2, q = p4 & 3;
            og4[p4] = *reinterpret_cast<const float4*>(&so[r * SO_STRIDE + q * 4]);
        }
    } else {
        for (int p = t; p < rows_here * 16; p += 256) {
            const int r = p >> 4, e = p & 15;
            og[p] = so[r * SO_STRIDE + e];
        }
    }
}

extern "C" void kernel_launch(void* const* d_in, const int* in_sizes, int n_in,
                              void* d_out, int out_size, void* d_ws, size_t ws_size,
                              hipStream_t stream) {
    const float* x  = (const float*)d_in[0];
    const float* w0 = (const float*)d_in[1];
    const float* w1 = (const float*)d_in[2];
    const float* w2 = (const float*)d_in[3];
    const float* w3 = (const float*)d_in[4];
    const float* b0 = (const float*)d_in[5];
    const float* kg = (const float*)d_in[6];
    float* out = (float*)d_out;

    const int nrows = in_sizes[0] / 9;   // B*C
    const int C = in_sizes[6] / 3;       // channels (k is (C,3))
    if (nrows <= 0) return;

    const int block = 256;
    const int grid = (nrows + block - 1) / block;
    hipLaunchKernelGGL(e3_selfmix_kernel, dim3(grid), dim3(block), 0, stream,
                       x, w0, w1, w2, w3, b0, kg, out, nrows, C);
}

// Round 4
// 37.984 us; speedup vs baseline: 1.0003x; 1.0003x over previous
//
#include <hip/hip_runtime.h>

// ---------------------------------------------------------------------------
// Compile-time Clebsch-Gordan machinery (direct port of the reference Python).
// All coefficients fold to FMA immediates in the kernel.
// ---------------------------------------------------------------------------

struct Cx { double r, i; };

constexpr double ffact(int n) {
    double v = 1.0;
    for (int i = 2; i <= n; ++i) v *= (double)i;
    return v;
}

constexpr double csqrt_(double x) {
    if (x <= 0.0) return 0.0;
    double g = x < 1.0 ? 1.0 : x;
    for (int i = 0; i < 48; ++i) g = 0.5 * (g + x / g);
    return g;
}

// Complex-basis CG <j1 m1 j2 m2 | j3 m3> (Racah formula), as in the reference.
constexpr double cgc(int j1, int m1, int j2, int m2, int j3, int m3) {
    if (m1 + m2 != m3) return 0.0;
    if (m1 < -j1 || m1 > j1 || m2 < -j2 || m2 > j2 || m3 < -j3 || m3 > j3) return 0.0;
    double pref = csqrt_((2.0 * j3 + 1.0) * ffact(j3 + j1 - j2) * ffact(j3 - j1 + j2) *
                         ffact(j1 + j2 - j3) / ffact(j1 + j2 + j3 + 1));
    pref *= csqrt_(ffact(j3 + m3) * ffact(j3 - m3) * ffact(j1 - m1) * ffact(j1 + m1) *
                   ffact(j2 - m2) * ffact(j2 + m2));
    double s = 0.0;
    for (int k = 0; k <= j1 + j2 - j3; ++k) {
        const int d0 = k, d1 = j1 + j2 - j3 - k, d2 = j1 - m1 - k;
        const int d3 = j2 + m2 - k, d4 = j3 - j2 + m1 + k, d5 = j3 - j1 - m2 + k;
        if (d0 < 0 || d1 < 0 || d2 < 0 || d3 < 0 || d4 < 0 || d5 < 0) continue;
        const double den = ffact(d0) * ffact(d1) * ffact(d2) * ffact(d3) * ffact(d4) * ffact(d5);
        s += ((k & 1) ? -1.0 : 1.0) / den;
    }
    return pref * s;
}

// Entry (row a, col m) of the complex->real change-of-basis matrix Q for level l.
constexpr Cx qent(int l, int a, int m) {
    Cx z{0.0, 0.0};
    if (l == 0) { if (a == 0 && m == 0) z.r = 1.0; return z; }
    if (a == l) { if (m == l) z.r = 1.0; return z; }
    const double is = 0.70710678118654752440;  // 1/sqrt(2)
    if (a > l) {
        const int mm = a - l;
        if (m == l + mm)      z.r = (mm & 1) ? -is : is;   // (-1)^m / sqrt2
        else if (m == l - mm) z.r = is;                    // 1 / sqrt2
    } else {
        const int mm = l - a;
        if (m == l - mm)      z.i = is;                    // i / sqrt2
        else if (m == l + mm) z.i = (mm & 1) ? is : -is;   // -i(-1)^m / sqrt2
    }
    return z;
}

// Real-basis CG tensor for one path (l1, l2) -> l3.
template <int L1, int L2, int L3>
struct PathT {
    double v[2 * L1 + 1][2 * L2 + 1][2 * L3 + 1];
    constexpr PathT() : v{} {
        double CG[2 * L1 + 1][2 * L2 + 1][2 * L3 + 1] = {};
        for (int m = 0; m <= 2 * L1; ++m)
            for (int n = 0; n <= 2 * L2; ++n)
                for (int o = 0; o <= 2 * L3; ++o)
                    CG[m][n][o] = cgc(L1, m - L1, L2, n - L2, L3, o - L3);
        Cx Q1[2 * L1 + 1][2 * L1 + 1] = {};
        Cx Q2[2 * L2 + 1][2 * L2 + 1] = {};
        Cx Q3[2 * L3 + 1][2 * L3 + 1] = {};
        for (int a = 0; a <= 2 * L1; ++a) for (int m = 0; m <= 2 * L1; ++m) Q1[a][m] = qent(L1, a, m);
        for (int b = 0; b <= 2 * L2; ++b) for (int n = 0; n <= 2 * L2; ++n) Q2[b][n] = qent(L2, b, n);
        for (int c = 0; c <= 2 * L3; ++c) for (int o = 0; o <= 2 * L3; ++o) Q3[c][o] = qent(L3, c, o);
        for (int a = 0; a <= 2 * L1; ++a)
            for (int b = 0; b <= 2 * L2; ++b)
                for (int c = 0; c <= 2 * L3; ++c) {
                    double re = 0.0;
                    for (int m = 0; m <= 2 * L1; ++m)
                        for (int n = 0; n <= 2 * L2; ++n)
                            for (int o = 0; o <= 2 * L3; ++o) {
                                const double cg = CG[m][n][o];
                                if (cg == 0.0) continue;
                                const Cx q1 = Q1[a][m], q2 = Q2[b][n], q3 = Q3[c][o];
                                const double tr = q1.r * q2.r - q1.i * q2.i;
                                const double ti = q1.r * q2.i + q1.i * q2.r;
                                re += (tr * q3.r + ti * q3.i) * cg;
                            }
                    v[a][b][c] = re;
                }
    }
};

static constexpr PathT<0, 0, 0> C000{};
static constexpr PathT<1, 1, 0> C110{};
static constexpr PathT<2, 2, 0> C220{};
static constexpr PathT<0, 1, 1> C011{};
static constexpr PathT<1, 0, 1> C101{};
static constexpr PathT<1, 2, 1> C121{};
static constexpr PathT<2, 1, 1> C211{};
static constexpr PathT<0, 2, 2> C022{};
static constexpr PathT<1, 1, 2> C112{};
static constexpr PathT<2, 0, 2> C202{};
static constexpr PathT<2, 2, 2> C222{};
static constexpr PathT<1, 2, 3> C123{};
static constexpr PathT<2, 1, 3> C213{};

static_assert(C000.v[0][0][0] > 0.999 && C000.v[0][0][0] < 1.001, "C000 must be 1");
static_assert(C110.v[0][0][0] < -0.577 && C110.v[0][0][0] > -0.578, "C110 diag must be -1/sqrt3");
static_assert(C110.v[0][1][0] > -1e-9 && C110.v[0][1][0] < 1e-9, "C110 off-diag must be 0");
static_assert(C220.v[2][2][0] > 0.447 && C220.v[2][2][0] < 0.448, "C220 diag must be +1/sqrt5");
static_assert(C011.v[0][1][1] > 0.999 && C011.v[0][1][1] < 1.001, "C011 must be identity");
static_assert(C022.v[0][3][3] > 0.999 && C022.v[0][3][3] < 1.001, "C022 must be identity");

// ---------------------------------------------------------------------------
// Per-row math (proven correct in round 1).
// ---------------------------------------------------------------------------

__device__ __forceinline__ void compute_row(const float* __restrict__ xs,
                                            const float* W0, const float* W1,
                                            const float* W2, const float* W3,
                                            float B0, float k0, float k1, float k2,
                                            float* __restrict__ o) {
    const float s = xs[0];

    // ---- l3 = 0 ----
    {
        const float z0 = (float)C000.v[0][0][0] * s * s;
        float z1 = 0.f;
#pragma unroll
        for (int a = 0; a < 3; ++a)
#pragma unroll
            for (int b = 0; b < 3; ++b) {
                const float cv = (float)C110.v[a][b][0];
                if (cv != 0.f) z1 += cv * xs[1 + a] * xs[1 + b];
            }
        float z2 = 0.f;
#pragma unroll
        for (int a = 0; a < 5; ++a)
#pragma unroll
            for (int b = 0; b < 5; ++b) {
                const float cv = (float)C220.v[a][b][0];
                if (cv != 0.f) z2 += cv * xs[4 + a] * xs[4 + b];
            }
        o[0] = (W0[0] * z0 + W0[1] * z1 + W0[2] * z2) * 0.57735026918962576f + B0 + k0 * s;
    }

    // ---- l3 = 1 ----
    {
        float za[3] = {}, zb[3] = {}, zc[3] = {}, zd[3] = {};
#pragma unroll
        for (int b = 0; b < 3; ++b)
#pragma unroll
            for (int c = 0; c < 3; ++c) {
                const float cv = (float)C011.v[0][b][c];
                if (cv != 0.f) za[c] += cv * s * xs[1 + b];
            }
#pragma unroll
        for (int a = 0; a < 3; ++a)
#pragma unroll
            for (int c = 0; c < 3; ++c) {
                const float cv = (float)C101.v[a][0][c];
                if (cv != 0.f) zb[c] += cv * xs[1 + a] * s;
            }
#pragma unroll
        for (int a = 0; a < 3; ++a)
#pragma unroll
            for (int b = 0; b < 5; ++b)
#pragma unroll
                for (int c = 0; c < 3; ++c) {
                    const float cv = (float)C121.v[a][b][c];
                    if (cv != 0.f) zc[c] += cv * xs[1 + a] * xs[4 + b];
                }
#pragma unroll
        for (int a = 0; a < 5; ++a)
#pragma unroll
            for (int b = 0; b < 3; ++b)
#pragma unroll
                for (int c = 0; c < 3; ++c) {
                    const float cv = (float)C211.v[a][b][c];
                    if (cv != 0.f) zd[c] += cv * xs[4 + a] * xs[1 + b];
                }
#pragma unroll
        for (int c = 0; c < 3; ++c)
            o[1 + c] = (W1[0] * za[c] + W1[1] * zb[c] + W1[2] * zc[c] + W1[3] * zd[c]) * 0.5f
                       + k1 * xs[1 + c];
    }

    // ---- l3 = 2 ----
    {
        float za[5] = {}, zb[5] = {}, zc[5] = {}, zd[5] = {};
#pragma unroll
        for (int b = 0; b < 5; ++b)
#pragma unroll
            for (int c = 0; c < 5; ++c) {
                const float cv = (float)C022.v[0][b][c];
                if (cv != 0.f) za[c] += cv * s * xs[4 + b];
            }
#pragma unroll
        for (int a = 0; a < 3; ++a)
#pragma unroll
            for (int b = 0; b < 3; ++b)
#pragma unroll
                for (int c = 0; c < 5; ++c) {
                    const float cv = (float)C112.v[a][b][c];
                    if (cv != 0.f) zb[c] += cv * xs[1 + a] * xs[1 + b];
                }
#pragma unroll
        for (int a = 0; a < 5; ++a)
#pragma unroll
            for (int c = 0; c < 5; ++c) {
                const float cv = (float)C202.v[a][0][c];
                if (cv != 0.f) zc[c] += cv * xs[4 + a] * s;
            }
#pragma unroll
        for (int a = 0; a < 5; ++a)
#pragma unroll
            for (int b = 0; b < 5; ++b)
#pragma unroll
                for (int c = 0; c < 5; ++c) {
                    const float cv = (float)C222.v[a][b][c];
                    if (cv != 0.f) zd[c] += cv * xs[4 + a] * xs[4 + b];
                }
#pragma unroll
        for (int c = 0; c < 5; ++c)
            o[4 + c] = (W2[0] * za[c] + W2[1] * zb[c] + W2[2] * zc[c] + W2[3] * zd[c]) * 0.5f
                       + k2 * xs[4 + c];
    }

    // ---- l3 = 3 ----
    {
        float za[7] = {}, zb[7] = {};
#pragma unroll
        for (int a = 0; a < 3; ++a)
#pragma unroll
            for (int b = 0; b < 5; ++b)
#pragma unroll
                for (int c = 0; c < 7; ++c) {
                    const float cv = (float)C123.v[a][b][c];
                    if (cv != 0.f) za[c] += cv * xs[1 + a] * xs[4 + b];
                }
#pragma unroll
        for (int a = 0; a < 5; ++a)
#pragma unroll
            for (int b = 0; b < 3; ++b)
#pragma unroll
                for (int c = 0; c < 7; ++c) {
                    const float cv = (float)C213.v[a][b][c];
                    if (cv != 0.f) zb[c] += cv * xs[4 + a] * xs[1 + b];
                }
#pragma unroll
        for (int c = 0; c < 7; ++c)
            o[9 + c] = (W3[0] * za[c] + W3[1] * zb[c]) * 0.70710678118654752440f;
    }
}

// ---------------------------------------------------------------------------
// Kernel: block of 256 threads handles 256 rows. All global traffic is fully
// coalesced via LDS staging. The x-staging buffer and the out-staging buffer
// ALIAS the same LDS region (temporally disjoint, enforced by a barrier after
// xs is copied to registers): LDS/block 31 KB -> 22 KB, residency 5 -> 7
// blocks/CU (28 waves, 87.5% occupancy) for better phase overlap.
// Out-staging row stride = 20 words (80 B): 16B-aligned (b128-legal); 20 mod
// 32 spreads 16B chunks uniformly over all 32 banks in both write (lane-major)
// and readback (row-major) phases -> conflict-free.
// ---------------------------------------------------------------------------

#define SO_STRIDE 20

__global__ __launch_bounds__(256) void e3_selfmix_kernel(
    const float* __restrict__ x, const float* __restrict__ w0,
    const float* __restrict__ w1, const float* __restrict__ w2,
    const float* __restrict__ w3, const float* __restrict__ b0,
    const float* __restrict__ kg, float* __restrict__ out,
    int nrows, int C) {
    __shared__ __align__(16) float smem[256 * SO_STRIDE];  // 20480 B (sx alias so)
    __shared__ __align__(16) float sk[384];                // 1536 B

    const int t = threadIdx.x;
    const long long blockBase = (long long)blockIdx.x * 256;
    const int rows_here = min(256, (int)(nrows - blockBase));
    const float* __restrict__ xg = x + blockBase * 9;
    float* __restrict__ og = out + blockBase * 16;

    // Wave-uniform parameters (compiler scalarizes; issue early).
    const float W0[3] = {w0[0], w0[1], w0[2]};
    const float W1[4] = {w1[0], w1[1], w1[2], w1[3]};
    const float W2[4] = {w2[0], w2[1], w2[2], w2[3]};
    const float W3[2] = {w3[0], w3[1]};
    const float B0 = b0[0];

    // ---- stage k (C==128: whole table, 96 coalesced float4 loads) ----
    const bool kfast = (C == 128);
    if (kfast && t < 96)
        *reinterpret_cast<float4*>(&sk[t * 4]) = reinterpret_cast<const float4*>(kg)[t];

    // ---- stage x into smem[0..2304): 576 float4, fully coalesced ----
    if (rows_here == 256) {
        const float4* __restrict__ xg4 = reinterpret_cast<const float4*>(xg);
#pragma unroll
        for (int i = 0; i < 3; ++i) {
            const int idx = i * 256 + t;
            if (idx < 576)
                *reinterpret_cast<float4*>(&smem[idx * 4]) = xg4[idx];
        }
    } else {
        for (int w = t; w < rows_here * 9; w += 256) smem[w] = xg[w];
    }
    __syncthreads();

    // ---- copy this thread's row to registers (stride-9 reads, <=2-way) ----
    float xs[9];
    if (t < rows_here) {
#pragma unroll
        for (int j = 0; j < 9; ++j) xs[j] = smem[t * 9 + j];
    }
    __syncthreads();  // all xs reads done -> smem reusable as out-staging

    // ---- compute + out-stage (aliased region) ----
    if (t < rows_here) {
        float k0, k1, k2;
        if (kfast) {
            const int ch3 = (t & 127) * 3;  // blockBase is a multiple of 128
            k0 = sk[ch3]; k1 = sk[ch3 + 1]; k2 = sk[ch3 + 2];
        } else {
            const long long ch = (blockBase + t) % C;
            k0 = kg[ch * 3]; k1 = kg[ch * 3 + 1]; k2 = kg[ch * 3 + 2];
        }

        float o[16];
        compute_row(xs, W0, W1, W2, W3, B0, k0, k1, k2, o);

        // 4x ds_write_b128; bank starts cycle all 8 disjoint 4-bank spans.
#pragma unroll
        for (int q = 0; q < 4; ++q)
            *reinterpret_cast<float4*>(&smem[t * SO_STRIDE + q * 4]) =
                make_float4(o[4 * q], o[4 * q + 1], o[4 * q + 2], o[4 * q + 3]);
    }
    __syncthreads();

    // ---- coalesced store: 4x ds_read_b128 + 4x global_store_dwordx4 ----
    if (rows_here == 256) {
        float4* __restrict__ og4 = reinterpret_cast<float4*>(og);
#pragma unroll
        for (int i = 0; i < 4; ++i) {
            const int p4 = i * 256 + t;          // float4 index: row p4>>2, quad p4&3
            const int r = p4 >> 2, q = p4 & 3;
            og4[p4] = *reinterpret_cast<const float4*>(&smem[r * SO_STRIDE + q * 4]);
        }
    } else {
        for (int p = t; p < rows_here * 16; p += 256) {
            const int r = p >> 4, e = p & 15;
            og[p] = smem[r * SO_STRIDE + e];
        }
    }
}

extern "C" void kernel_launch(void* const* d_in, const int* in_sizes, int n_in,
                              void* d_out, int out_size, void* d_ws, size_t ws_size,
                              hipStream_t stream) {
    const float* x  = (const float*)d_in[0];
    const float* w0 = (const float*)d_in[1];
    const float* w1 = (const float*)d_in[2];
    const float* w2 = (const float*)d_in[3];
    const float* w3 = (const float*)d_in[4];
    const float* b0 = (const float*)d_in[5];
    const float* kg = (const float*)d_in[6];
    float* out = (float*)d_out;

    const int nrows = in_sizes[0] / 9;   // B*C
    const int C = in_sizes[6] / 3;       // channels (k is (C,3))
    if (nrows <= 0) return;

    const int block = 256;
    const int grid = (nrows + block - 1) / block;
    hipLaunchKernelGGL(e3_selfmix_kernel, dim3(grid), dim3(block), 0, stream,
                       x, w0, w1, w2, w3, b0, kg, out, nrows, C);
}

// Round 5
// 37.668 us; speedup vs baseline: 1.0087x; 1.0084x over previous
//
#include <hip/hip_runtime.h>

// ---------------------------------------------------------------------------
// Compile-time Clebsch-Gordan machinery (direct port of the reference Python).
// All coefficients fold to FMA immediates in the kernel.
// ---------------------------------------------------------------------------

struct Cx { double r, i; };

constexpr double ffact(int n) {
    double v = 1.0;
    for (int i = 2; i <= n; ++i) v *= (double)i;
    return v;
}

constexpr double csqrt_(double x) {
    if (x <= 0.0) return 0.0;
    double g = x < 1.0 ? 1.0 : x;
    for (int i = 0; i < 48; ++i) g = 0.5 * (g + x / g);
    return g;
}

// Complex-basis CG <j1 m1 j2 m2 | j3 m3> (Racah formula), as in the reference.
constexpr double cgc(int j1, int m1, int j2, int m2, int j3, int m3) {
    if (m1 + m2 != m3) return 0.0;
    if (m1 < -j1 || m1 > j1 || m2 < -j2 || m2 > j2 || m3 < -j3 || m3 > j3) return 0.0;
    double pref = csqrt_((2.0 * j3 + 1.0) * ffact(j3 + j1 - j2) * ffact(j3 - j1 + j2) *
                         ffact(j1 + j2 - j3) / ffact(j1 + j2 + j3 + 1));
    pref *= csqrt_(ffact(j3 + m3) * ffact(j3 - m3) * ffact(j1 - m1) * ffact(j1 + m1) *
                   ffact(j2 - m2) * ffact(j2 + m2));
    double s = 0.0;
    for (int k = 0; k <= j1 + j2 - j3; ++k) {
        const int d0 = k, d1 = j1 + j2 - j3 - k, d2 = j1 - m1 - k;
        const int d3 = j2 + m2 - k, d4 = j3 - j2 + m1 + k, d5 = j3 - j1 - m2 + k;
        if (d0 < 0 || d1 < 0 || d2 < 0 || d3 < 0 || d4 < 0 || d5 < 0) continue;
        const double den = ffact(d0) * ffact(d1) * ffact(d2) * ffact(d3) * ffact(d4) * ffact(d5);
        s += ((k & 1) ? -1.0 : 1.0) / den;
    }
    return pref * s;
}

// Entry (row a, col m) of the complex->real change-of-basis matrix Q for level l.
constexpr Cx qent(int l, int a, int m) {
    Cx z{0.0, 0.0};
    if (l == 0) { if (a == 0 && m == 0) z.r = 1.0; return z; }
    if (a == l) { if (m == l) z.r = 1.0; return z; }
    const double is = 0.70710678118654752440;  // 1/sqrt(2)
    if (a > l) {
        const int mm = a - l;
        if (m == l + mm)      z.r = (mm & 1) ? -is : is;   // (-1)^m / sqrt2
        else if (m == l - mm) z.r = is;                    // 1 / sqrt2
    } else {
        const int mm = l - a;
        if (m == l - mm)      z.i = is;                    // i / sqrt2
        else if (m == l + mm) z.i = (mm & 1) ? is : -is;   // -i(-1)^m / sqrt2
    }
    return z;
}

// Real-basis CG tensor for one path (l1, l2) -> l3.
template <int L1, int L2, int L3>
struct PathT {
    double v[2 * L1 + 1][2 * L2 + 1][2 * L3 + 1];
    constexpr PathT() : v{} {
        double CG[2 * L1 + 1][2 * L2 + 1][2 * L3 + 1] = {};
        for (int m = 0; m <= 2 * L1; ++m)
            for (int n = 0; n <= 2 * L2; ++n)
                for (int o = 0; o <= 2 * L3; ++o)
                    CG[m][n][o] = cgc(L1, m - L1, L2, n - L2, L3, o - L3);
        Cx Q1[2 * L1 + 1][2 * L1 + 1] = {};
        Cx Q2[2 * L2 + 1][2 * L2 + 1] = {};
        Cx Q3[2 * L3 + 1][2 * L3 + 1] = {};
        for (int a = 0; a <= 2 * L1; ++a) for (int m = 0; m <= 2 * L1; ++m) Q1[a][m] = qent(L1, a, m);
        for (int b = 0; b <= 2 * L2; ++b) for (int n = 0; n <= 2 * L2; ++n) Q2[b][n] = qent(L2, b, n);
        for (int c = 0; c <= 2 * L3; ++c) for (int o = 0; o <= 2 * L3; ++o) Q3[c][o] = qent(L3, c, o);
        for (int a = 0; a <= 2 * L1; ++a)
            for (int b = 0; b <= 2 * L2; ++b)
                for (int c = 0; c <= 2 * L3; ++c) {
                    double re = 0.0;
                    for (int m = 0; m <= 2 * L1; ++m)
                        for (int n = 0; n <= 2 * L2; ++n)
                            for (int o = 0; o <= 2 * L3; ++o) {
                                const double cg = CG[m][n][o];
                                if (cg == 0.0) continue;
                                const Cx q1 = Q1[a][m], q2 = Q2[b][n], q3 = Q3[c][o];
                                const double tr = q1.r * q2.r - q1.i * q2.i;
                                const double ti = q1.r * q2.i + q1.i * q2.r;
                                re += (tr * q3.r + ti * q3.i) * cg;
                            }
                    v[a][b][c] = re;
                }
    }
};

static constexpr PathT<0, 0, 0> C000{};
static constexpr PathT<1, 1, 0> C110{};
static constexpr PathT<2, 2, 0> C220{};
static constexpr PathT<0, 1, 1> C011{};
static constexpr PathT<1, 0, 1> C101{};
static constexpr PathT<1, 2, 1> C121{};
static constexpr PathT<2, 1, 1> C211{};
static constexpr PathT<0, 2, 2> C022{};
static constexpr PathT<1, 1, 2> C112{};
static constexpr PathT<2, 0, 2> C202{};
static constexpr PathT<2, 2, 2> C222{};
static constexpr PathT<1, 2, 3> C123{};
static constexpr PathT<2, 1, 3> C213{};

static_assert(C000.v[0][0][0] > 0.999 && C000.v[0][0][0] < 1.001, "C000 must be 1");
static_assert(C110.v[0][0][0] < -0.577 && C110.v[0][0][0] > -0.578, "C110 diag must be -1/sqrt3");
static_assert(C110.v[0][1][0] > -1e-9 && C110.v[0][1][0] < 1e-9, "C110 off-diag must be 0");
static_assert(C220.v[2][2][0] > 0.447 && C220.v[2][2][0] < 0.448, "C220 diag must be +1/sqrt5");
static_assert(C011.v[0][1][1] > 0.999 && C011.v[0][1][1] < 1.001, "C011 must be identity");
static_assert(C022.v[0][3][3] > 0.999 && C022.v[0][3][3] < 1.001, "C022 must be identity");

// ---------------------------------------------------------------------------
// Per-row math (proven correct in round 1).
// ---------------------------------------------------------------------------

__device__ __forceinline__ void compute_row(const float* __restrict__ xs,
                                            const float* W0, const float* W1,
                                            const float* W2, const float* W3,
                                            float B0, float k0, float k1, float k2,
                                            float* __restrict__ o) {
    const float s = xs[0];

    // ---- l3 = 0 ----
    {
        const float z0 = (float)C000.v[0][0][0] * s * s;
        float z1 = 0.f;
#pragma unroll
        for (int a = 0; a < 3; ++a)
#pragma unroll
            for (int b = 0; b < 3; ++b) {
                const float cv = (float)C110.v[a][b][0];
                if (cv != 0.f) z1 += cv * xs[1 + a] * xs[1 + b];
            }
        float z2 = 0.f;
#pragma unroll
        for (int a = 0; a < 5; ++a)
#pragma unroll
            for (int b = 0; b < 5; ++b) {
                const float cv = (float)C220.v[a][b][0];
                if (cv != 0.f) z2 += cv * xs[4 + a] * xs[4 + b];
            }
        o[0] = (W0[0] * z0 + W0[1] * z1 + W0[2] * z2) * 0.57735026918962576f + B0 + k0 * s;
    }

    // ---- l3 = 1 ----
    {
        float za[3] = {}, zb[3] = {}, zc[3] = {}, zd[3] = {};
#pragma unroll
        for (int b = 0; b < 3; ++b)
#pragma unroll
            for (int c = 0; c < 3; ++c) {
                const float cv = (float)C011.v[0][b][c];
                if (cv != 0.f) za[c] += cv * s * xs[1 + b];
            }
#pragma unroll
        for (int a = 0; a < 3; ++a)
#pragma unroll
            for (int c = 0; c < 3; ++c) {
                const float cv = (float)C101.v[a][0][c];
                if (cv != 0.f) zb[c] += cv * xs[1 + a] * s;
            }
#pragma unroll
        for (int a = 0; a < 3; ++a)
#pragma unroll
            for (int b = 0; b < 5; ++b)
#pragma unroll
                for (int c = 0; c < 3; ++c) {
                    const float cv = (float)C121.v[a][b][c];
                    if (cv != 0.f) zc[c] += cv * xs[1 + a] * xs[4 + b];
                }
#pragma unroll
        for (int a = 0; a < 5; ++a)
#pragma unroll
            for (int b = 0; b < 3; ++b)
#pragma unroll
                for (int c = 0; c < 3; ++c) {
                    const float cv = (float)C211.v[a][b][c];
                    if (cv != 0.f) zd[c] += cv * xs[4 + a] * xs[1 + b];
                }
#pragma unroll
        for (int c = 0; c < 3; ++c)
            o[1 + c] = (W1[0] * za[c] + W1[1] * zb[c] + W1[2] * zc[c] + W1[3] * zd[c]) * 0.5f
                       + k1 * xs[1 + c];
    }

    // ---- l3 = 2 ----
    {
        float za[5] = {}, zb[5] = {}, zc[5] = {}, zd[5] = {};
#pragma unroll
        for (int b = 0; b < 5; ++b)
#pragma unroll
            for (int c = 0; c < 5; ++c) {
                const float cv = (float)C022.v[0][b][c];
                if (cv != 0.f) za[c] += cv * s * xs[4 + b];
            }
#pragma unroll
        for (int a = 0; a < 3; ++a)
#pragma unroll
            for (int b = 0; b < 3; ++b)
#pragma unroll
                for (int c = 0; c < 5; ++c) {
                    const float cv = (float)C112.v[a][b][c];
                    if (cv != 0.f) zb[c] += cv * xs[1 + a] * xs[1 + b];
                }
#pragma unroll
        for (int a = 0; a < 5; ++a)
#pragma unroll
            for (int c = 0; c < 5; ++c) {
                const float cv = (float)C202.v[a][0][c];
                if (cv != 0.f) zc[c] += cv * xs[4 + a] * s;
            }
#pragma unroll
        for (int a = 0; a < 5; ++a)
#pragma unroll
            for (int b = 0; b < 5; ++b)
#pragma unroll
                for (int c = 0; c < 5; ++c) {
                    const float cv = (float)C222.v[a][b][c];
                    if (cv != 0.f) zd[c] += cv * xs[4 + a] * xs[4 + b];
                }
#pragma unroll
        for (int c = 0; c < 5; ++c)
            o[4 + c] = (W2[0] * za[c] + W2[1] * zb[c] + W2[2] * zc[c] + W2[3] * zd[c]) * 0.5f
                       + k2 * xs[4 + c];
    }

    // ---- l3 = 3 ----
    {
        float za[7] = {}, zb[7] = {};
#pragma unroll
        for (int a = 0; a < 3; ++a)
#pragma unroll
            for (int b = 0; b < 5; ++b)
#pragma unroll
                for (int c = 0; c < 7; ++c) {
                    const float cv = (float)C123.v[a][b][c];
                    if (cv != 0.f) za[c] += cv * xs[1 + a] * xs[4 + b];
                }
#pragma unroll
        for (int a = 0; a < 5; ++a)
#pragma unroll
            for (int b = 0; b < 3; ++b)
#pragma unroll
                for (int c = 0; c < 7; ++c) {
                    const float cv = (float)C213.v[a][b][c];
                    if (cv != 0.f) zb[c] += cv * xs[4 + a] * xs[1 + b];
                }
#pragma unroll
        for (int c = 0; c < 7; ++c)
            o[9 + c] = (W3[0] * za[c] + W3[1] * zb[c]) * 0.70710678118654752440f;
    }
}

// ---------------------------------------------------------------------------
// Kernel: block of 256 threads handles 256 rows. All global traffic is fully
// coalesced via LDS staging; x-staging and out-staging alias one LDS region
// (22 KB -> 7 blocks/CU). Output stores are NONTEMPORAL (`nt`): the 134 MB
// write stream bypasses L2/L3 allocation so x (75.5 MB) stays L3-resident
// across graph replays instead of being thrashed by the write stream.
// Out-staging row stride = 20 words (80 B): 16B-aligned (b128-legal); 20 mod
// 32 spreads 16B chunks uniformly over all 32 banks in both phases.
// ---------------------------------------------------------------------------

#define SO_STRIDE 20

using f32x4 = __attribute__((ext_vector_type(4))) float;

__global__ __launch_bounds__(256) void e3_selfmix_kernel(
    const float* __restrict__ x, const float* __restrict__ w0,
    const float* __restrict__ w1, const float* __restrict__ w2,
    const float* __restrict__ w3, const float* __restrict__ b0,
    const float* __restrict__ kg, float* __restrict__ out,
    int nrows, int C) {
    __shared__ __align__(16) float smem[256 * SO_STRIDE];  // 20480 B (sx alias so)
    __shared__ __align__(16) float sk[384];                // 1536 B

    const int t = threadIdx.x;
    const long long blockBase = (long long)blockIdx.x * 256;
    const int rows_here = min(256, (int)(nrows - blockBase));
    const float* __restrict__ xg = x + blockBase * 9;
    float* __restrict__ og = out + blockBase * 16;

    // Wave-uniform parameters (compiler scalarizes; issue early).
    const float W0[3] = {w0[0], w0[1], w0[2]};
    const float W1[4] = {w1[0], w1[1], w1[2], w1[3]};
    const float W2[4] = {w2[0], w2[1], w2[2], w2[3]};
    const float W3[2] = {w3[0], w3[1]};
    const float B0 = b0[0];

    // ---- stage k (C==128: whole table, 96 coalesced float4 loads) ----
    const bool kfast = (C == 128);
    if (kfast && t < 96)
        *reinterpret_cast<float4*>(&sk[t * 4]) = reinterpret_cast<const float4*>(kg)[t];

    // ---- stage x into smem[0..2304): 576 float4, fully coalesced ----
    if (rows_here == 256) {
        const float4* __restrict__ xg4 = reinterpret_cast<const float4*>(xg);
#pragma unroll
        for (int i = 0; i < 3; ++i) {
            const int idx = i * 256 + t;
            if (idx < 576)
                *reinterpret_cast<float4*>(&smem[idx * 4]) = xg4[idx];
        }
    } else {
        for (int w = t; w < rows_here * 9; w += 256) smem[w] = xg[w];
    }
    __syncthreads();

    // ---- copy this thread's row to registers (stride-9 reads, <=2-way) ----
    float xs[9];
    if (t < rows_here) {
#pragma unroll
        for (int j = 0; j < 9; ++j) xs[j] = smem[t * 9 + j];
    }
    __syncthreads();  // all xs reads done -> smem reusable as out-staging

    // ---- compute + out-stage (aliased region) ----
    if (t < rows_here) {
        float k0, k1, k2;
        if (kfast) {
            const int ch3 = (t & 127) * 3;  // blockBase is a multiple of 128
            k0 = sk[ch3]; k1 = sk[ch3 + 1]; k2 = sk[ch3 + 2];
        } else {
            const long long ch = (blockBase + t) % C;
            k0 = kg[ch * 3]; k1 = kg[ch * 3 + 1]; k2 = kg[ch * 3 + 2];
        }

        float o[16];
        compute_row(xs, W0, W1, W2, W3, B0, k0, k1, k2, o);

        // 4x ds_write_b128; bank starts cycle all 8 disjoint 4-bank spans.
#pragma unroll
        for (int q = 0; q < 4; ++q)
            *reinterpret_cast<float4*>(&smem[t * SO_STRIDE + q * 4]) =
                make_float4(o[4 * q], o[4 * q + 1], o[4 * q + 2], o[4 * q + 3]);
    }
    __syncthreads();

    // ---- coalesced store: 4x ds_read_b128 + 4x nontemporal dwordx4 ----
    if (rows_here == 256) {
        f32x4* __restrict__ og4 = reinterpret_cast<f32x4*>(og);
#pragma unroll
        for (int i = 0; i < 4; ++i) {
            const int p4 = i * 256 + t;          // float4 index: row p4>>2, quad p4&3
            const int r = p4 >> 2, q = p4 & 3;
            const f32x4 v = *reinterpret_cast<const f32x4*>(&smem[r * SO_STRIDE + q * 4]);
            __builtin_nontemporal_store(v, og4 + p4);
        }
    } else {
        for (int p = t; p < rows_here * 16; p += 256) {
            const int r = p >> 4, e = p & 15;
            __builtin_nontemporal_store(smem[r * SO_STRIDE + e], og + p);
        }
    }
}

extern "C" void kernel_launch(void* const* d_in, const int* in_sizes, int n_in,
                              void* d_out, int out_size, void* d_ws, size_t ws_size,
                              hipStream_t stream) {
    const float* x  = (const float*)d_in[0];
    const float* w0 = (const float*)d_in[1];
    const float* w1 = (const float*)d_in[2];
    const float* w2 = (const float*)d_in[3];
    const float* w3 = (const float*)d_in[4];
    const float* b0 = (const float*)d_in[5];
    const float* kg = (const float*)d_in[6];
    float* out = (float*)d_out;

    const int nrows = in_sizes[0] / 9;   // B*C
    const int C = in_sizes[6] / 3;       // channels (k is (C,3))
    if (nrows <= 0) return;

    const int block = 256;
    const int grid = (nrows + block - 1) / block;
    hipLaunchKernelGGL(e3_selfmix_kernel, dim3(grid), dim3(block), 0, stream,
                       x, w0, w1, w2, w3, b0, kg, out, nrows, C);
}